// Round 5
// baseline (655.064 us; speedup 1.0000x reference)
//
#include <hip/hip_runtime.h>
#include <math.h>

#define B_  4
#define S_  2048
#define D_  1024
#define H_  16
#define DH_ 64
#define DF_ 4096
#define M_  8192   // B*S

// 0.125 (1/sqrt(DH)) * log2(e): folded into Q so softmax = exp2(score)
#define QSC 0.18033688011112042f

typedef __attribute__((ext_vector_type(8))) short bf8_t;   // 8 x bf16 (4 VGPRs)
typedef __attribute__((ext_vector_type(4))) float f4_t;    // 4 x f32

__device__ __forceinline__ unsigned short f2bf(float x) {
  union { float f; unsigned u; } v; v.f = x;
  unsigned r = v.u + 0x7fffu + ((v.u >> 16) & 1u);   // RNE
  return (unsigned short)(r >> 16);
}

#if defined(__has_builtin)
#if __has_builtin(__builtin_amdgcn_cvt_pk_bf16_f32)
#define HAVE_PKCVT 1
#endif
#if __has_builtin(__builtin_amdgcn_global_load_lds)
#define HAVE_ASYNC 1
#endif
#endif

// pack two f32 -> two bf16 in one u32 (v_cvt_pk_bf16_f32 on gfx950)
__device__ __forceinline__ unsigned pk_bf16(float lo, float hi) {
#ifdef HAVE_PKCVT
  auto r = __builtin_amdgcn_cvt_pk_bf16_f32(lo, hi);
  unsigned u; __builtin_memcpy(&u, &r, 4); return u;
#else
  return (unsigned)f2bf(lo) | ((unsigned)f2bf(hi) << 16);
#endif
}

__device__ __forceinline__ bf8_t upk8(unsigned u0, unsigned u1, unsigned u2, unsigned u3) {
  union { unsigned u[4]; bf8_t v; } c;
  c.u[0] = u0; c.u[1] = u1; c.u[2] = u2; c.u[3] = u3; return c.v;
}

__device__ __forceinline__ f4_t mfma32(bf8_t a, bf8_t b, f4_t c) {
  return __builtin_amdgcn_mfma_f32_16x16x32_bf16(a, b, c, 0, 0, 0);
}

__device__ __forceinline__ void async16(const void* g, void* l) {
#ifdef HAVE_ASYNC
  __builtin_amdgcn_global_load_lds((__attribute__((address_space(1))) void*)(g),
                                   (__attribute__((address_space(3))) void*)(l), 16, 0, 0);
#else
  *(uint4*)l = *(const uint4*)g;
#endif
}

// XOR swizzle for 64-short (128 B) rows: 16-B chunk c of row r lives at
// physical chunk c ^ sw(r). Balances ds_read across all 32 banks.
__device__ __forceinline__ int sw(int row) { return (row ^ (row >> 3)) & 7; }

// ---------------- weight prep ----------------

// generic fp32 [K][N] -> bf16 [N][K]
__global__ __launch_bounds__(256) void wtrans_kernel(const float* __restrict__ in,
                                                     unsigned short* __restrict__ out,
                                                     int K, int N) {
  const int k0 = blockIdx.x * 32, n0 = blockIdx.y * 32;
  __shared__ float t[32][33];
  const int tid = threadIdx.x;
#pragma unroll
  for (int i = 0; i < 4; i++) {
    int idx = i * 256 + tid; int r = idx >> 5, c = idx & 31;
    t[r][c] = in[(size_t)(k0 + r) * N + n0 + c];
  }
  __syncthreads();
#pragma unroll
  for (int i = 0; i < 4; i++) {
    int idx = i * 256 + tid; int r = idx >> 5, c = idx & 31;
    out[(size_t)(n0 + r) * K + k0 + c] = f2bf(t[c][r]);
  }
}

// Wq/Wk/Wv [H][D][DH] -> WqkvT [3072][1024]  (row n = sel*1024 + h*64 + e, col k = d)
__global__ __launch_bounds__(256) void qkvpack_kernel(const float* __restrict__ Wq,
                                                      const float* __restrict__ Wk,
                                                      const float* __restrict__ Wv,
                                                      unsigned short* __restrict__ WqkvT) {
  const int z = blockIdx.z;            // 0..47
  const int sel = z >> 4, h = z & 15;
  const float* in = (sel == 0 ? Wq : sel == 1 ? Wk : Wv) + (size_t)h * D_ * DH_;
  const int k0 = blockIdx.x * 32, n0 = blockIdx.y * 32;   // k over D, n over DH
  __shared__ float t[32][33];
  const int tid = threadIdx.x;
#pragma unroll
  for (int i = 0; i < 4; i++) {
    int idx = i * 256 + tid; int r = idx >> 5, c = idx & 31;
    t[r][c] = in[(size_t)(k0 + r) * DH_ + n0 + c];
  }
  __syncthreads();
#pragma unroll
  for (int i = 0; i < 4; i++) {
    int idx = i * 256 + tid; int r = idx >> 5, c = idx & 31;
    int n = sel * 1024 + h * 64 + n0 + r;
    WqkvT[(size_t)n * D_ + k0 + c] = f2bf(t[c][r]);
  }
}

__global__ void biaspack_kernel(const float* __restrict__ bq, const float* __restrict__ bk,
                                const float* __restrict__ bv, float* __restrict__ bqkv) {
  int i = blockIdx.x * 256 + threadIdx.x;
  if (i < 3072) {
    int sel = i >> 10, j = i & 1023;
    const float* src = sel == 0 ? bq : sel == 1 ? bk : bv;
    bqkv[i] = src[j];
  }
}

// ---------------- layernorm (fp32 in -> bf16 out) ----------------

__global__ __launch_bounds__(256) void ln_kernel(const float* __restrict__ x,
                                                 const float* __restrict__ w,
                                                 const float* __restrict__ bb,
                                                 unsigned short* __restrict__ out) {
  const int row = blockIdx.x;
  const float* xr = x + (size_t)row * D_;
  const int tid = threadIdx.x;
  float v[4]; float s = 0.f;
#pragma unroll
  for (int i = 0; i < 4; i++) { v[i] = xr[tid + i * 256]; s += v[i]; }
  __shared__ float red[8];
#pragma unroll
  for (int o = 32; o; o >>= 1) s += __shfl_xor(s, o, 64);
  const int wv = tid >> 6, ln = tid & 63;
  if (!ln) red[wv] = s;
  __syncthreads();
  float mean = (red[0] + red[1] + red[2] + red[3]) * (1.f / 1024.f);
  float s2 = 0.f;
#pragma unroll
  for (int i = 0; i < 4; i++) { float d = v[i] - mean; s2 += d * d; }
#pragma unroll
  for (int o = 32; o; o >>= 1) s2 += __shfl_xor(s2, o, 64);
  if (!ln) red[4 + wv] = s2;
  __syncthreads();
  float var = (red[4] + red[5] + red[6] + red[7]) * (1.f / 1024.f);
  float rstd = rsqrtf(var + 1e-5f);
#pragma unroll
  for (int i = 0; i < 4; i++) {
    int c = tid + i * 256;
    out[(size_t)row * D_ + c] = f2bf((v[i] - mean) * rstd * w[c] + bb[c]);
  }
}

// ---------------- GEMM: C = A[M,K](bf16) x Bt[N,K](bf16)^T + epilogue ----------------
// m97 structure: 128x128 tile, BK=32, 4 waves (2x2), 4x4 mfma_16x16x32_bf16 per wave.
// EPI 0: +bias -> bf16 out; q-part (n<1024) scaled by QSC (QKV only)
// EPI 1: +bias +resid -> f32 out
// EPI 2: +bias, exact gelu -> bf16 out
template <int EPI>
__global__ __launch_bounds__(256) void gemm_bt(const unsigned short* __restrict__ A,
                                               const unsigned short* __restrict__ Bt,
                                               const float* __restrict__ bias,
                                               const float* __restrict__ resid,
                                               unsigned short* __restrict__ outb,
                                               float* __restrict__ outf,
                                               int Ndim, int Kdim) {
  __shared__ __align__(16) unsigned short Asmem[4096];   // [128][32]
  __shared__ __align__(16) unsigned short Bsmem[4096];   // [128][32]
  const int tid = threadIdx.x;
  const int wave = tid >> 6, lane = tid & 63;
  const int quad = lane >> 4, l16 = lane & 15;
  const int wm = wave >> 1, wn = wave & 1;
  const int m0 = blockIdx.y * 128, n0 = blockIdx.x * 128;

  const f4_t fzero = {0.f, 0.f, 0.f, 0.f};
  f4_t acc[4][4];
#pragma unroll
  for (int i = 0; i < 4; i++)
#pragma unroll
    for (int j = 0; j < 4; j++) acc[i][j] = fzero;

  const int rowA = tid >> 2;            // 0..63
  const int kp = (tid & 3) * 8;         // 0,8,16,24

  for (int k0 = 0; k0 < Kdim; k0 += 32) {
    __syncthreads();
#pragma unroll
    for (int r = 0; r < 2; r++) {
      const int row = r * 64 + rowA;
      const int e = row * 32 + kp;
      async16(A  + (size_t)(m0 + row) * Kdim + k0 + kp, &Asmem[e]);
      async16(Bt + (size_t)(n0 + row) * Kdim + k0 + kp, &Bsmem[e]);
    }
    __syncthreads();

    bf8_t a[4], b[4];
#pragma unroll
    for (int i = 0; i < 4; i++) {
      a[i] = *(const bf8_t*)&Asmem[(wm * 64 + i * 16 + l16) * 32 + quad * 8];
      b[i] = *(const bf8_t*)&Bsmem[(wn * 64 + i * 16 + l16) * 32 + quad * 8];
    }
#pragma unroll
    for (int i = 0; i < 4; i++)
#pragma unroll
      for (int j = 0; j < 4; j++)
        acc[i][j] = mfma32(a[i], b[j], acc[i][j]);
  }

  const float sc = (EPI == 0 && n0 < 1024) ? QSC : 1.f;
#pragma unroll
  for (int i = 0; i < 4; i++) {
#pragma unroll
    for (int j = 0; j < 4; j++) {
#pragma unroll
      for (int r = 0; r < 4; r++) {
        const int m = m0 + wm * 64 + i * 16 + quad * 4 + r;
        const int n = n0 + wn * 64 + j * 16 + l16;
        float v = acc[i][j][r] + bias[n];
        if constexpr (EPI == 0) v *= sc;
        if constexpr (EPI == 2) v = 0.5f * v * (1.f + erff(v * 0.70710678118654752f));
        if constexpr (EPI == 1) {
          v += resid[(size_t)m * Ndim + n];
          outf[(size_t)m * Ndim + n] = v;
        } else {
          outb[(size_t)m * Ndim + n] = f2bf(v);
        }
      }
    }
  }
}

// ---------------- V transpose: qkv v-part [b,t,h,e] -> vT [b,h,e,perm(t)] ----------
// t-columns permuted within each aligned 64-block so attn's K=32 PV B-frag slot
// order (k=quad*8+j from two stacked C-layout 16-blocks) matches V's contraction
// order: g(t) = (t&32) + 8*((t>>2)&3) + 4*((t>>4)&1) + (t&3).

__global__ __launch_bounds__(256) void vtrans_kernel(const unsigned short* __restrict__ qkv,
                                                     unsigned short* __restrict__ vT) {
  const int bh = blockIdx.y, b = bh >> 4, h = bh & 15;
  const int t0 = blockIdx.x * 64;
  __shared__ unsigned short tile[64][65];
  const int tid = threadIdx.x;
#pragma unroll
  for (int i = 0; i < 16; i++) {
    int idx = i * 256 + tid;
    int t = idx >> 6, e = idx & 63;
    tile[e][t] = qkv[(size_t)(b * S_ + t0 + t) * 3072 + 2048 + h * 64 + e];
  }
  __syncthreads();
#pragma unroll
  for (int i = 0; i < 16; i++) {
    int idx = i * 256 + tid;
    int e = idx >> 6, t = idx & 63;
    int gt = (t & 32) + 8 * ((t >> 2) & 3) + 4 * ((t >> 4) & 1) + (t & 3);
    vT[(size_t)(bh * 64 + e) * S_ + t0 + gt] = tile[e][t];
  }
}

// ---------------- flash attention ----------------
// 256 threads (4 waves), 128 q-rows/block; wave owns 32 s as 2x16 blocks.
// S^T = mfma(A=K, B=Q): P exits QK^T in PV B-operand layout (K=32 via the
// vtrans t-permutation) -> PV is pure mfma32, V A-frags as single b128 reads.
// Q pre-scaled by QSC in GEMM -> p = exp2(sf) directly; mask folded into the
// accumulator init (0 / -8e9); l via an extra ones-MFMA (no shuffles).
// SINGLE-buffer staging with the proven two-barrier pattern (R4's prefetch
// single-barrier dbuf raced: vmcnt drain of global_load_lds across the barrier
// is dependence-based, and the cross-iteration LDS alias was not honored).

__global__ __launch_bounds__(256) void attn_kernel(const unsigned short* __restrict__ qkv,
                                                   const unsigned short* __restrict__ vT,
                                                   const int* __restrict__ maskp,
                                                   unsigned short* __restrict__ attended) {
  const int bh = blockIdx.y, b = bh >> 4, h = bh & 15;
  const int q0 = blockIdx.x * 128;
  const int tid = threadIdx.x, wv = tid >> 6, lane = tid & 63;
  const int quad = lane >> 4, l16 = lane & 15;
  __shared__ __align__(16) unsigned short smem[9216];  // Ks[4096] | Vs[4096]; Os overlay
  __shared__ float biasl[64];
  unsigned short* Ks = smem;
  unsigned short* Vs = smem + 4096;

  // Q fragments straight from global (one-time; B-operand layout k=quad*8+j)
  bf8_t aq[2][2];
#pragma unroll
  for (int sb = 0; sb < 2; sb++) {
    const unsigned short* qrow =
        qkv + (size_t)(b * S_ + q0 + wv * 32 + sb * 16 + l16) * 3072 + h * 64;
    aq[sb][0] = *(const bf8_t*)(qrow + quad * 8);
    aq[sb][1] = *(const bf8_t*)(qrow + 32 + quad * 8);
  }

  const bf8_t ones8 = {0x3F80, 0x3F80, 0x3F80, 0x3F80, 0x3F80, 0x3F80, 0x3F80, 0x3F80};
  const f4_t fzero = {0.f, 0.f, 0.f, 0.f};
  f4_t o[2][4], lacc[2];
#pragma unroll
  for (int sb = 0; sb < 2; sb++) {
    lacc[sb] = fzero;
#pragma unroll
    for (int ee = 0; ee < 4; ee++) o[sb][ee] = fzero;
  }

  for (int t0 = 0; t0 < S_; t0 += 64) {
    __syncthreads();   // all waves done reading the previous K/V tile
#pragma unroll
    for (int r = 0; r < 2; r++) {
      int ci = r * 256 + tid;
      int row = ci >> 3, lc = (ci & 7) ^ sw(row);
      async16(qkv + (size_t)(b * S_ + t0 + row) * 3072 + 1024 + h * 64 + lc * 8, &Ks[ci * 8]);
      async16(vT + (size_t)(bh * 64 + row) * S_ + t0 + lc * 8, &Vs[ci * 8]);
    }
    if (tid < 64) biasl[tid] = maskp[b * S_ + t0 + tid] ? 0.f : -8e9f;
    __syncthreads();   // staged tile visible (vmcnt drained at barrier)

    // S^T tiles: sf[sb][jj][r] = score^T[t=16jj+4quad+r][s=block+l16] + maskbias
    f4_t sf[2][4];
#pragma unroll
    for (int jj = 0; jj < 4; jj++) {
      f4_t bi = *(const f4_t*)&biasl[jj * 16 + quad * 4];
      sf[0][jj] = bi;
      sf[1][jj] = bi;
    }
#pragma unroll
    for (int jj = 0; jj < 4; jj++) {
      int krow = jj * 16 + l16, sk = sw(krow);
      bf8_t kf0 = *(const bf8_t*)&Ks[krow * 64 + (quad ^ sk) * 8];
      bf8_t kf1 = *(const bf8_t*)&Ks[krow * 64 + ((quad + 4) ^ sk) * 8];
      sf[0][jj] = mfma32(kf0, aq[0][0], sf[0][jj]);
      sf[0][jj] = mfma32(kf1, aq[0][1], sf[0][jj]);
      sf[1][jj] = mfma32(kf0, aq[1][0], sf[1][jj]);
      sf[1][jj] = mfma32(kf1, aq[1][1], sf[1][jj]);
    }

    // p = exp2(sf); pack straight into K=32 B-frags (jj even -> j0..3, odd -> j4..7)
    bf8_t pp[2][2];
#pragma unroll
    for (int sb = 0; sb < 2; sb++) {
#pragma unroll
      for (int h2 = 0; h2 < 2; h2++) {
        float p0 = exp2f(sf[sb][2 * h2][0]),     p1 = exp2f(sf[sb][2 * h2][1]);
        float p2 = exp2f(sf[sb][2 * h2][2]),     p3 = exp2f(sf[sb][2 * h2][3]);
        float p4 = exp2f(sf[sb][2 * h2 + 1][0]), p5 = exp2f(sf[sb][2 * h2 + 1][1]);
        float p6 = exp2f(sf[sb][2 * h2 + 1][2]), p7 = exp2f(sf[sb][2 * h2 + 1][3]);
        pp[sb][h2] = upk8(pk_bf16(p0, p1), pk_bf16(p2, p3),
                          pk_bf16(p4, p5), pk_bf16(p6, p7));
      }
      lacc[sb] = mfma32(ones8, pp[sb][0], lacc[sb]);
      lacc[sb] = mfma32(ones8, pp[sb][1], lacc[sb]);
    }

    // O^T += V^T x P^T: pure K=32 MFMAs, V-frags single b128 (reused across sb)
#pragma unroll
    for (int ee = 0; ee < 4; ee++) {
      int vrow = ee * 16 + l16, sv = sw(vrow);
#pragma unroll
      for (int h2 = 0; h2 < 2; h2++) {
        bf8_t vf = *(const bf8_t*)&Vs[vrow * 64 + ((4 * h2 + quad) ^ sv) * 8];
        o[0][ee] = mfma32(vf, pp[0][h2], o[0][ee]);
        o[1][ee] = mfma32(vf, pp[1][h2], o[1][ee]);
      }
    }
  }

  float linv[2];
#pragma unroll
  for (int sb = 0; sb < 2; sb++) linv[sb] = 1.f / lacc[sb][0];

  // transpose O^T -> row-major via LDS overlay (pad 72), coalesced 16-B stores
  __syncthreads();                       // last tile's readers done before overlay
  unsigned short* Os = smem;             // [128][72] = 9216 shorts
#pragma unroll
  for (int sb = 0; sb < 2; sb++) {
    int srow = wv * 32 + sb * 16 + l16;
#pragma unroll
    for (int ee = 0; ee < 4; ee++) {
      unsigned w0 = pk_bf16(o[sb][ee][0] * linv[sb], o[sb][ee][1] * linv[sb]);
      unsigned w1 = pk_bf16(o[sb][ee][2] * linv[sb], o[sb][ee][3] * linv[sb]);
      uint2 wq; wq.x = w0; wq.y = w1;
      *(uint2*)&Os[srow * 72 + ee * 16 + quad * 4] = wq;
    }
  }
  __syncthreads();
#pragma unroll
  for (int it = 0; it < 4; it++) {
    int row = it * 32 + (tid >> 3), e0 = (tid & 7) * 8;
    bf8_t v = *(const bf8_t*)&Os[row * 72 + e0];
    *(bf8_t*)&attended[(size_t)(b * S_ + q0 + row) * D_ + h * 64 + e0] = v;
  }
}

// ---------------- launcher ----------------

extern "C" void kernel_launch(void* const* d_in, const int* in_sizes, int n_in,
                              void* d_out, int out_size, void* d_ws, size_t ws_size,
                              hipStream_t stream) {
  const float* state = (const float*)d_in[0];
  const int*   maskp = (const int*)d_in[1];
  const float* ln1w  = (const float*)d_in[2];
  const float* ln1b  = (const float*)d_in[3];
  const float* Wq    = (const float*)d_in[4];
  const float* bq    = (const float*)d_in[5];
  const float* Wk    = (const float*)d_in[6];
  const float* bk    = (const float*)d_in[7];
  const float* Wv    = (const float*)d_in[8];
  const float* bv    = (const float*)d_in[9];
  const float* Wo    = (const float*)d_in[10];
  const float* bo    = (const float*)d_in[11];
  const float* ln2w  = (const float*)d_in[12];
  const float* ln2b  = (const float*)d_in[13];
  const float* W1    = (const float*)d_in[14];
  const float* b1    = (const float*)d_in[15];
  const float* W2    = (const float*)d_in[16];
  const float* b2    = (const float*)d_in[17];

  // workspace carve-up (total ~136 MiB; ff1 aliases the dead qkv+vT region)
  char* w = (char*)d_ws;
  unsigned short* hidden = (unsigned short*)w; w += (size_t)M_ * D_ * 2;      // 16 MiB
  unsigned short* qkv    = (unsigned short*)w; w += (size_t)M_ * 3072 * 2;    // 48 MiB
  unsigned short* vT     = (unsigned short*)w; w += (size_t)M_ * D_ * 2;      // 16 MiB
  float*          outp   = (float*)w;          w += (size_t)M_ * D_ * 4;      // 32 MiB
  unsigned short* WqkvT  = (unsigned short*)w; w += (size_t)3072 * D_ * 2;    //  6 MiB
  unsigned short* WoT    = (unsigned short*)w; w += (size_t)D_ * D_ * 2;      //  2 MiB
  unsigned short* W1T    = (unsigned short*)w; w += (size_t)DF_ * D_ * 2;     //  8 MiB
  unsigned short* W2T    = (unsigned short*)w; w += (size_t)D_ * DF_ * 2;     //  8 MiB
  float*          bqkv   = (float*)w;          w += 3072 * 4;
  unsigned short* ff1    = qkv;                // 64 MiB alias: qkv/vT dead before FFN1

  // weight prep
  qkvpack_kernel<<<dim3(32, 2, 48), 256, 0, stream>>>(Wq, Wk, Wv, WqkvT);
  wtrans_kernel<<<dim3(32, 32), 256, 0, stream>>>(Wo, WoT, D_, D_);
  wtrans_kernel<<<dim3(32, 128), 256, 0, stream>>>(W1, W1T, D_, DF_);
  wtrans_kernel<<<dim3(128, 32), 256, 0, stream>>>(W2, W2T, DF_, D_);
  biaspack_kernel<<<12, 256, 0, stream>>>(bq, bk, bv, bqkv);

  // attention block
  ln_kernel<<<M_, 256, 0, stream>>>(state, ln1w, ln1b, hidden);
  gemm_bt<0><<<dim3(3072 / 128, M_ / 128), 256, 0, stream>>>(hidden, WqkvT, bqkv, nullptr,
                                                             qkv, nullptr, 3072, D_);
  vtrans_kernel<<<dim3(S_ / 64, B_ * H_), 256, 0, stream>>>(qkv, vT);
  attn_kernel<<<dim3(S_ / 128, B_ * H_), 256, 0, stream>>>(qkv, vT, maskp, hidden);
  gemm_bt<1><<<dim3(D_ / 128, M_ / 128), 256, 0, stream>>>(hidden, WoT, bo, state,
                                                           nullptr, outp, D_, D_);
  // FFN block
  ln_kernel<<<M_, 256, 0, stream>>>(outp, ln2w, ln2b, hidden);
  gemm_bt<2><<<dim3(DF_ / 128, M_ / 128), 256, 0, stream>>>(hidden, W1T, b1, nullptr,
                                                            ff1, nullptr, DF_, D_);
  gemm_bt<1><<<dim3(D_ / 128, M_ / 128), 256, 0, stream>>>(ff1, W2T, b2, outp,
                                                           nullptr, (float*)d_out, D_, DF_);
}

// Round 6
// 613.363 us; speedup vs baseline: 1.0680x; 1.0680x over previous
//
#include <hip/hip_runtime.h>
#include <math.h>

#define B_  4
#define S_  2048
#define D_  1024
#define H_  16
#define DH_ 64
#define DF_ 4096
#define M_  8192   // B*S

// 0.125 (1/sqrt(DH)) * log2(e): folded into Q so softmax = exp2(score)
#define QSC 0.18033688011112042f

typedef __attribute__((ext_vector_type(8))) short bf8_t;   // 8 x bf16 (4 VGPRs)
typedef __attribute__((ext_vector_type(4))) float f4_t;    // 4 x f32

#if defined(__has_builtin)
#if __has_builtin(__builtin_amdgcn_cvt_pk_bf16_f32)
#define HAVE_PKCVT 1
#endif
#if __has_builtin(__builtin_amdgcn_global_load_lds)
#define HAVE_ASYNC 1
#endif
#if __has_builtin(__builtin_amdgcn_exp2f)
#define EXP2F(x) __builtin_amdgcn_exp2f(x)
#else
#define EXP2F(x) __expf((x) * 0.69314718055994531f)
#endif
#else
#define EXP2F(x) __expf((x) * 0.69314718055994531f)
#endif

// pack two f32 -> two bf16 in one u32 (v_cvt_pk_bf16_f32 on gfx950)
__device__ __forceinline__ unsigned pk_bf16(float lo, float hi) {
#ifdef HAVE_PKCVT
  auto r = __builtin_amdgcn_cvt_pk_bf16_f32(lo, hi);
  unsigned u; __builtin_memcpy(&u, &r, 4); return u;
#else
  union { float f; unsigned u; } a, b2; a.f = lo; b2.f = hi;
  unsigned ra = a.u + 0x7fffu + ((a.u >> 16) & 1u);
  unsigned rb = b2.u + 0x7fffu + ((b2.u >> 16) & 1u);
  return (ra >> 16) | (rb & 0xffff0000u);
#endif
}

__device__ __forceinline__ unsigned short f2bf(float x) {
  return (unsigned short)(pk_bf16(x, x) & 0xffffu);
}

__device__ __forceinline__ bf8_t upk8(unsigned u0, unsigned u1, unsigned u2, unsigned u3) {
  union { unsigned u[4]; bf8_t v; } c;
  c.u[0] = u0; c.u[1] = u1; c.u[2] = u2; c.u[3] = u3; return c.v;
}

__device__ __forceinline__ f4_t mfma32(bf8_t a, bf8_t b, f4_t c) {
  return __builtin_amdgcn_mfma_f32_16x16x32_bf16(a, b, c, 0, 0, 0);
}

__device__ __forceinline__ void async16(const void* g, void* l) {
#ifdef HAVE_ASYNC
  __builtin_amdgcn_global_load_lds((__attribute__((address_space(1))) void*)(g),
                                   (__attribute__((address_space(3))) void*)(l), 16, 0, 0);
#else
  *(uint4*)l = *(const uint4*)g;
#endif
}

// XOR swizzle for 64-short (128 B) row groups: 16-B chunk c of row r lives at
// physical chunk c ^ sw(r). Balances ds_read across all 32 banks.
__device__ __forceinline__ int sw(int row) { return (row ^ (row >> 3)) & 7; }

// ---------------- weight prep ----------------

// generic fp32 [K][N] -> bf16 [N][K]
__global__ __launch_bounds__(256) void wtrans_kernel(const float* __restrict__ in,
                                                     unsigned short* __restrict__ out,
                                                     int K, int N) {
  const int k0 = blockIdx.x * 32, n0 = blockIdx.y * 32;
  __shared__ float t[32][33];
  const int tid = threadIdx.x;
#pragma unroll
  for (int i = 0; i < 4; i++) {
    int idx = i * 256 + tid; int r = idx >> 5, c = idx & 31;
    t[r][c] = in[(size_t)(k0 + r) * N + n0 + c];
  }
  __syncthreads();
#pragma unroll
  for (int i = 0; i < 4; i++) {
    int idx = i * 256 + tid; int r = idx >> 5, c = idx & 31;
    out[(size_t)(n0 + r) * K + k0 + c] = f2bf(t[c][r]);
  }
}

// Wq/Wk/Wv [H][D][DH] -> WqkvT [3072][1024]  (row n = sel*1024 + h*64 + e, col k = d)
__global__ __launch_bounds__(256) void qkvpack_kernel(const float* __restrict__ Wq,
                                                      const float* __restrict__ Wk,
                                                      const float* __restrict__ Wv,
                                                      unsigned short* __restrict__ WqkvT) {
  const int z = blockIdx.z;            // 0..47
  const int sel = z >> 4, h = z & 15;
  const float* in = (sel == 0 ? Wq : sel == 1 ? Wk : Wv) + (size_t)h * D_ * DH_;
  const int k0 = blockIdx.x * 32, n0 = blockIdx.y * 32;   // k over D, n over DH
  __shared__ float t[32][33];
  const int tid = threadIdx.x;
#pragma unroll
  for (int i = 0; i < 4; i++) {
    int idx = i * 256 + tid; int r = idx >> 5, c = idx & 31;
    t[r][c] = in[(size_t)(k0 + r) * DH_ + n0 + c];
  }
  __syncthreads();
#pragma unroll
  for (int i = 0; i < 4; i++) {
    int idx = i * 256 + tid; int r = idx >> 5, c = idx & 31;
    int n = sel * 1024 + h * 64 + n0 + r;
    WqkvT[(size_t)n * D_ + k0 + c] = f2bf(t[c][r]);
  }
}

__global__ void biaspack_kernel(const float* __restrict__ bq, const float* __restrict__ bk,
                                const float* __restrict__ bv, float* __restrict__ bqkv) {
  int i = blockIdx.x * 256 + threadIdx.x;
  if (i < 3072) {
    int sel = i >> 10, j = i & 1023;
    const float* src = sel == 0 ? bq : sel == 1 ? bk : bv;
    bqkv[i] = src[j];
  }
}

// ---------------- layernorm (fp32 in -> bf16 out) ----------------

__global__ __launch_bounds__(256) void ln_kernel(const float* __restrict__ x,
                                                 const float* __restrict__ w,
                                                 const float* __restrict__ bb,
                                                 unsigned short* __restrict__ out) {
  const int row = blockIdx.x;
  const float* xr = x + (size_t)row * D_;
  const int tid = threadIdx.x;
  float v[4]; float s = 0.f;
#pragma unroll
  for (int i = 0; i < 4; i++) { v[i] = xr[tid + i * 256]; s += v[i]; }
  __shared__ float red[8];
#pragma unroll
  for (int o = 32; o; o >>= 1) s += __shfl_xor(s, o, 64);
  const int wv = tid >> 6, ln = tid & 63;
  if (!ln) red[wv] = s;
  __syncthreads();
  float mean = (red[0] + red[1] + red[2] + red[3]) * (1.f / 1024.f);
  float s2 = 0.f;
#pragma unroll
  for (int i = 0; i < 4; i++) { float d = v[i] - mean; s2 += d * d; }
#pragma unroll
  for (int o = 32; o; o >>= 1) s2 += __shfl_xor(s2, o, 64);
  if (!ln) red[4 + wv] = s2;
  __syncthreads();
  float var = (red[4] + red[5] + red[6] + red[7]) * (1.f / 1024.f);
  float rstd = rsqrtf(var + 1e-5f);
#pragma unroll
  for (int i = 0; i < 4; i++) {
    int c = tid + i * 256;
    out[(size_t)row * D_ + c] = f2bf((v[i] - mean) * rstd * w[c] + bb[c]);
  }
}

// ---------------- GEMM: C = A[M,K](bf16) x Bt[N,K](bf16)^T + epilogue ----------------
// m97 structure: 128x128 tile, BK=32, 4 waves (2x2), 4x4 mfma_16x16x32_bf16 per wave.
// EPI 0 (QKV): +bias; n<1024 (Q) scaled by QSC -> bf16 qkv; n>=2048 (V) written
//              transposed+permuted straight into vT (replaces vtrans kernel).
// EPI 1: +bias +resid -> f32 out
// EPI 2: +bias, exact gelu -> bf16 out
template <int EPI>
__global__ __launch_bounds__(256) void gemm_bt(const unsigned short* __restrict__ A,
                                               const unsigned short* __restrict__ Bt,
                                               const float* __restrict__ bias,
                                               const float* __restrict__ resid,
                                               unsigned short* __restrict__ outb,
                                               float* __restrict__ outf,
                                               unsigned short* __restrict__ vTout,
                                               int Ndim, int Kdim) {
  __shared__ __align__(16) unsigned short Asmem[4096];   // [128][32]
  __shared__ __align__(16) unsigned short Bsmem[4096];   // [128][32]
  const int tid = threadIdx.x;
  const int wave = tid >> 6, lane = tid & 63;
  const int quad = lane >> 4, l16 = lane & 15;
  const int wm = wave >> 1, wn = wave & 1;
  const int m0 = blockIdx.y * 128, n0 = blockIdx.x * 128;

  const f4_t fzero = {0.f, 0.f, 0.f, 0.f};
  f4_t acc[4][4];
#pragma unroll
  for (int i = 0; i < 4; i++)
#pragma unroll
    for (int j = 0; j < 4; j++) acc[i][j] = fzero;

  const int rowA = tid >> 2;            // 0..63
  const int kp = (tid & 3) * 8;         // 0,8,16,24

  for (int k0 = 0; k0 < Kdim; k0 += 32) {
    __syncthreads();
#pragma unroll
    for (int r = 0; r < 2; r++) {
      const int row = r * 64 + rowA;
      const int e = row * 32 + kp;
      async16(A  + (size_t)(m0 + row) * Kdim + k0 + kp, &Asmem[e]);
      async16(Bt + (size_t)(n0 + row) * Kdim + k0 + kp, &Bsmem[e]);
    }
    __syncthreads();

    bf8_t a[4], b[4];
#pragma unroll
    for (int i = 0; i < 4; i++) {
      a[i] = *(const bf8_t*)&Asmem[(wm * 64 + i * 16 + l16) * 32 + quad * 8];
      b[i] = *(const bf8_t*)&Bsmem[(wn * 64 + i * 16 + l16) * 32 + quad * 8];
    }
#pragma unroll
    for (int i = 0; i < 4; i++)
#pragma unroll
      for (int j = 0; j < 4; j++)
        acc[i][j] = mfma32(a[i], b[j], acc[i][j]);
  }

  if (EPI == 0 && n0 >= 2048) {
    // V region -> vT[(b*16+h)*64+e][ (s&~63) + g(s&63) ], 4 consecutive t per lane
    const int bb2 = m0 >> 11;                       // batch (tile never crosses)
    const int s_base = (m0 & 2047) + wm * 64;       // 64-aligned
#pragma unroll
    for (int i = 0; i < 4; i++) {
      const int g0 = (i & 2) * 16 + 8 * quad + 4 * (i & 1);
#pragma unroll
      for (int j = 0; j < 4; j++) {
        const int n = n0 + wn * 64 + j * 16 + l16;
        const int ef = n - 2048;
        const int hh = ef >> 6, e = ef & 63;
        const float bsv = bias[n];
        uint2 wq;
        wq.x = pk_bf16(acc[i][j][0] + bsv, acc[i][j][1] + bsv);
        wq.y = pk_bf16(acc[i][j][2] + bsv, acc[i][j][3] + bsv);
        *(uint2*)&vTout[(size_t)((bb2 * 16 + hh) * 64 + e) * S_ + s_base + g0] = wq;
      }
    }
    return;
  }

  const float sc = (EPI == 0 && n0 < 1024) ? QSC : 1.f;
#pragma unroll
  for (int i = 0; i < 4; i++) {
#pragma unroll
    for (int j = 0; j < 4; j++) {
#pragma unroll
      for (int r = 0; r < 4; r++) {
        const int m = m0 + wm * 64 + i * 16 + quad * 4 + r;
        const int n = n0 + wn * 64 + j * 16 + l16;
        float v = acc[i][j][r] + bias[n];
        if constexpr (EPI == 0) v *= sc;
        if constexpr (EPI == 2) v = 0.5f * v * (1.f + erff(v * 0.70710678118654752f));
        if constexpr (EPI == 1) {
          v += resid[(size_t)m * Ndim + n];
          outf[(size_t)m * Ndim + n] = v;
        } else {
          outb[(size_t)m * Ndim + n] = f2bf(v);
        }
      }
    }
  }
}

// ---------------- flash attention ----------------
// 256 threads (4 waves), 128 q-rows/block; wave owns 32 s as 2x16 blocks.
// S^T = mfma(A=K, B=Q): P exits QK^T in PV B-operand layout (K=32 via the
// t-permutation baked into vT by the QKV epilogue) -> PV is pure mfma32.
// Q pre-scaled by QSC in GEMM -> p = exp2(sf) via v_exp_f32; mask folded into
// accumulator init (0 / -8e9); l via ones-MFMA. 128-key tiles per stage
// (2-barrier proven pattern, halved barrier count vs 64-key tiles).

__global__ __launch_bounds__(256) void attn_kernel(const unsigned short* __restrict__ qkv,
                                                   const unsigned short* __restrict__ vT,
                                                   const int* __restrict__ maskp,
                                                   unsigned short* __restrict__ attended) {
  const int bh = blockIdx.y, b = bh >> 4, h = bh & 15;
  const int q0 = blockIdx.x * 128;
  const int tid = threadIdx.x, wv = tid >> 6, lane = tid & 63;
  const int quad = lane >> 4, l16 = lane & 15;
  __shared__ __align__(16) unsigned short smem[16384];  // Ks[128][64] | Vs[64][128]
  __shared__ float biasl[128];
  unsigned short* Ks = smem;            // [128 t][64 e], per-row swizzle
  unsigned short* Vs = smem + 8192;     // [64 e][128 t], per-64-half swizzle

  // Q fragments straight from global (one-time; B-operand layout k=quad*8+j)
  bf8_t aq[2][2];
#pragma unroll
  for (int sb = 0; sb < 2; sb++) {
    const unsigned short* qrow =
        qkv + (size_t)(b * S_ + q0 + wv * 32 + sb * 16 + l16) * 3072 + h * 64;
    aq[sb][0] = *(const bf8_t*)(qrow + quad * 8);
    aq[sb][1] = *(const bf8_t*)(qrow + 32 + quad * 8);
  }

  const bf8_t ones8 = {0x3F80, 0x3F80, 0x3F80, 0x3F80, 0x3F80, 0x3F80, 0x3F80, 0x3F80};
  const f4_t fzero = {0.f, 0.f, 0.f, 0.f};
  f4_t o[2][4], lacc[2];
#pragma unroll
  for (int sb = 0; sb < 2; sb++) {
    lacc[sb] = fzero;
#pragma unroll
    for (int ee = 0; ee < 4; ee++) o[sb][ee] = fzero;
  }

  for (int t0 = 0; t0 < S_; t0 += 128) {
    __syncthreads();   // all waves done reading the previous K/V tile
    // Ks: 1024 chunks (row = ci>>3, c = ci&7); Vs: 1024 chunks (e = ci>>4,
    // half = (ci>>3)&1, c = ci&7). Swizzle applied on the global source.
#pragma unroll
    for (int r = 0; r < 4; r++) {
      int ci = r * 256 + tid;
      int krow = ci >> 3, kc = (ci & 7) ^ sw(krow);
      async16(qkv + (size_t)(b * S_ + t0 + krow) * 3072 + 1024 + h * 64 + kc * 8,
              &Ks[ci * 8]);
      int e = ci >> 4, half = (ci >> 3) & 1, vc = (ci & 7) ^ sw(e);
      async16(vT + (size_t)(bh * 64 + e) * S_ + t0 + half * 64 + vc * 8,
              &Vs[ci * 8]);
    }
    if (tid < 128) biasl[tid] = maskp[b * S_ + t0 + tid] ? 0.f : -8e9f;
    __syncthreads();   // staged tile visible (vmcnt drained at barrier)

#pragma unroll
    for (int th = 0; th < 2; th++) {
      // S^T: sf[sb][jj][r] = score^T[t=th*64+16jj+4quad+r][s=block+l16] + maskbias
      f4_t sf[2][4];
#pragma unroll
      for (int jj = 0; jj < 4; jj++) {
        f4_t bi = *(const f4_t*)&biasl[th * 64 + jj * 16 + quad * 4];
        sf[0][jj] = bi;
        sf[1][jj] = bi;
      }
#pragma unroll
      for (int jj = 0; jj < 4; jj++) {
        int krow = th * 64 + jj * 16 + l16, sk = sw(krow);
        bf8_t kf0 = *(const bf8_t*)&Ks[krow * 64 + (quad ^ sk) * 8];
        bf8_t kf1 = *(const bf8_t*)&Ks[krow * 64 + ((quad + 4) ^ sk) * 8];
        sf[0][jj] = mfma32(kf0, aq[0][0], sf[0][jj]);
        sf[0][jj] = mfma32(kf1, aq[0][1], sf[0][jj]);
        sf[1][jj] = mfma32(kf0, aq[1][0], sf[1][jj]);
        sf[1][jj] = mfma32(kf1, aq[1][1], sf[1][jj]);
      }

      // p = exp2(sf); pack straight into K=32 B-frags
      bf8_t pp[2][2];
#pragma unroll
      for (int sb = 0; sb < 2; sb++) {
#pragma unroll
        for (int h2 = 0; h2 < 2; h2++) {
          float p0 = EXP2F(sf[sb][2 * h2][0]),     p1 = EXP2F(sf[sb][2 * h2][1]);
          float p2 = EXP2F(sf[sb][2 * h2][2]),     p3 = EXP2F(sf[sb][2 * h2][3]);
          float p4 = EXP2F(sf[sb][2 * h2 + 1][0]), p5 = EXP2F(sf[sb][2 * h2 + 1][1]);
          float p6 = EXP2F(sf[sb][2 * h2 + 1][2]), p7 = EXP2F(sf[sb][2 * h2 + 1][3]);
          pp[sb][h2] = upk8(pk_bf16(p0, p1), pk_bf16(p2, p3),
                            pk_bf16(p4, p5), pk_bf16(p6, p7));
        }
        lacc[sb] = mfma32(ones8, pp[sb][0], lacc[sb]);
        lacc[sb] = mfma32(ones8, pp[sb][1], lacc[sb]);
      }

      // O^T += V^T x P^T: pure K=32 MFMAs, V-frags single b128 (reused across sb)
#pragma unroll
      for (int ee = 0; ee < 4; ee++) {
        int vrow = ee * 16 + l16, sv = sw(vrow);
#pragma unroll
        for (int h2 = 0; h2 < 2; h2++) {
          bf8_t vf = *(const bf8_t*)&Vs[vrow * 128 + th * 64 + ((4 * h2 + quad) ^ sv) * 8];
          o[0][ee] = mfma32(vf, pp[0][h2], o[0][ee]);
          o[1][ee] = mfma32(vf, pp[1][h2], o[1][ee]);
        }
      }
    }
  }

  float linv[2];
#pragma unroll
  for (int sb = 0; sb < 2; sb++) linv[sb] = 1.f / lacc[sb][0];

  // transpose O^T -> row-major via LDS overlay (pad 72), coalesced 16-B stores
  __syncthreads();                       // last tile's readers done before overlay
  unsigned short* Os = smem;             // [128][72] = 9216 shorts
#pragma unroll
  for (int sb = 0; sb < 2; sb++) {
    int srow = wv * 32 + sb * 16 + l16;
#pragma unroll
    for (int ee = 0; ee < 4; ee++) {
      unsigned w0 = pk_bf16(o[sb][ee][0] * linv[sb], o[sb][ee][1] * linv[sb]);
      unsigned w1 = pk_bf16(o[sb][ee][2] * linv[sb], o[sb][ee][3] * linv[sb]);
      uint2 wq; wq.x = w0; wq.y = w1;
      *(uint2*)&Os[srow * 72 + ee * 16 + quad * 4] = wq;
    }
  }
  __syncthreads();
#pragma unroll
  for (int it = 0; it < 4; it++) {
    int row = it * 32 + (tid >> 3), e0 = (tid & 7) * 8;
    bf8_t v = *(const bf8_t*)&Os[row * 72 + e0];
    *(bf8_t*)&attended[(size_t)(b * S_ + q0 + row) * D_ + h * 64 + e0] = v;
  }
}

// ---------------- launcher ----------------

extern "C" void kernel_launch(void* const* d_in, const int* in_sizes, int n_in,
                              void* d_out, int out_size, void* d_ws, size_t ws_size,
                              hipStream_t stream) {
  const float* state = (const float*)d_in[0];
  const int*   maskp = (const int*)d_in[1];
  const float* ln1w  = (const float*)d_in[2];
  const float* ln1b  = (const float*)d_in[3];
  const float* Wq    = (const float*)d_in[4];
  const float* bq    = (const float*)d_in[5];
  const float* Wk    = (const float*)d_in[6];
  const float* bk    = (const float*)d_in[7];
  const float* Wv    = (const float*)d_in[8];
  const float* bv    = (const float*)d_in[9];
  const float* Wo    = (const float*)d_in[10];
  const float* bo    = (const float*)d_in[11];
  const float* ln2w  = (const float*)d_in[12];
  const float* ln2b  = (const float*)d_in[13];
  const float* W1    = (const float*)d_in[14];
  const float* b1    = (const float*)d_in[15];
  const float* W2    = (const float*)d_in[16];
  const float* b2    = (const float*)d_in[17];

  // workspace carve-up (total ~136 MiB; ff1 aliases the dead qkv+vT region)
  char* w = (char*)d_ws;
  unsigned short* hidden = (unsigned short*)w; w += (size_t)M_ * D_ * 2;      // 16 MiB
  unsigned short* qkv    = (unsigned short*)w; w += (size_t)M_ * 3072 * 2;    // 48 MiB
  unsigned short* vT     = (unsigned short*)w; w += (size_t)M_ * D_ * 2;      // 16 MiB
  float*          outp   = (float*)w;          w += (size_t)M_ * D_ * 4;      // 32 MiB
  unsigned short* WqkvT  = (unsigned short*)w; w += (size_t)3072 * D_ * 2;    //  6 MiB
  unsigned short* WoT    = (unsigned short*)w; w += (size_t)D_ * D_ * 2;      //  2 MiB
  unsigned short* W1T    = (unsigned short*)w; w += (size_t)DF_ * D_ * 2;     //  8 MiB
  unsigned short* W2T    = (unsigned short*)w; w += (size_t)D_ * DF_ * 2;     //  8 MiB
  float*          bqkv   = (float*)w;          w += 3072 * 4;
  unsigned short* ff1    = qkv;                // 64 MiB alias: qkv/vT dead before FFN1

  // weight prep
  qkvpack_kernel<<<dim3(32, 2, 48), 256, 0, stream>>>(Wq, Wk, Wv, WqkvT);
  wtrans_kernel<<<dim3(32, 32), 256, 0, stream>>>(Wo, WoT, D_, D_);
  wtrans_kernel<<<dim3(32, 128), 256, 0, stream>>>(W1, W1T, D_, DF_);
  wtrans_kernel<<<dim3(128, 32), 256, 0, stream>>>(W2, W2T, DF_, D_);
  biaspack_kernel<<<12, 256, 0, stream>>>(bq, bk, bv, bqkv);

  // attention block (V transposed into vT by the QKV epilogue)
  ln_kernel<<<M_, 256, 0, stream>>>(state, ln1w, ln1b, hidden);
  gemm_bt<0><<<dim3(3072 / 128, M_ / 128), 256, 0, stream>>>(hidden, WqkvT, bqkv, nullptr,
                                                             qkv, nullptr, vT, 3072, D_);
  attn_kernel<<<dim3(S_ / 128, B_ * H_), 256, 0, stream>>>(qkv, vT, maskp, hidden);
  gemm_bt<1><<<dim3(D_ / 128, M_ / 128), 256, 0, stream>>>(hidden, WoT, bo, state,
                                                           nullptr, outp, nullptr, D_, D_);
  // FFN block
  ln_kernel<<<M_, 256, 0, stream>>>(outp, ln2w, ln2b, hidden);
  gemm_bt<2><<<dim3(DF_ / 128, M_ / 128), 256, 0, stream>>>(hidden, W1T, b1, nullptr,
                                                            ff1, nullptr, nullptr, DF_, D_);
  gemm_bt<1><<<dim3(D_ / 128, M_ / 128), 256, 0, stream>>>(ff1, W2T, b2, outp,
                                                           nullptr, (float*)d_out, nullptr, D_, DF_);
}